// Round 3
// baseline (156.563 us; speedup 1.0000x reference)
//
#include <hip/hip_runtime.h>
#include <hip/hip_bf16.h>

#define B_ 8
#define DIN 16
#define L_ 4096
#define D_ 512
#define NP 4104
#define NG 342
#define JS 513
#define IPAD 4352

__device__ __forceinline__ unsigned short f2bf(float f) {
  unsigned int u = __float_as_uint(f);
  unsigned int r = (u + 0x7fffu + ((u >> 16) & 1u)) >> 16;
  return (unsigned short)r;
}
__device__ __forceinline__ float bf2f(unsigned int u) {
  return __uint_as_float(u << 16);
}

// ---------------- Kernel 1: conv -> h (bf16) ----------------
__global__ __launch_bounds__(256) void k_conv(
    const float* __restrict__ x, const float* __restrict__ cw,
    const float* __restrict__ cb, unsigned short* __restrict__ h) {
  __shared__ float ws_w[64 * 132];
  __shared__ float ws_x[DIN * 40];
  int bid = blockIdx.x;
  int dtile = bid & 3;
  int ntile = (bid >> 2) & 127;
  int b = bid >> 9;
  int n0 = ntile * 32;
  int d0 = dtile * 128;
  int tid = threadIdx.x;

  for (int q = tid; q < 128 * 16; q += 256) {
    int dd = q >> 4, qq = (q & 15) << 2;
    float4 wv = *reinterpret_cast<const float4*>(cw + ((size_t)(d0 + dd) << 6) + qq);
    *reinterpret_cast<float4*>(&ws_w[(dd >> 1) * 132 + (dd & 1) * 64 + qq]) = wv;
  }
  const float* xb = x + (size_t)b * DIN * L_;
  for (int q = tid; q < DIN * 40; q += 256) {
    int i = q / 40, c = q - i * 40;
    int nx = n0 + c - 4;
    ws_x[q] = (nx >= 0 && nx < L_) ? xb[i * L_ + nx] : 0.0f;
  }
  __syncthreads();

  int dp = tid & 63;
  int seg = tid >> 6;
  float acc0[8], acc1[8];
#pragma unroll
  for (int j = 0; j < 8; ++j) { acc0[j] = 0.f; acc1[j] = 0.f; }

  for (int i = 0; i < DIN; ++i) {
    const float* wp = &ws_w[dp * 132 + (i << 2)];
    float w00 = wp[0], w01 = wp[1], w02 = wp[2], w03 = wp[3];
    float w10 = wp[64], w11 = wp[65], w12 = wp[66], w13 = wp[67];
    const float* xp = &ws_x[i * 40 + (seg << 3)];
    float xr[16];
#pragma unroll
    for (int m = 0; m < 16; ++m) xr[m] = xp[m];
#pragma unroll
    for (int j = 0; j < 8; ++j) {
      float a0 = acc0[j], a1 = acc1[j];
      a0 = fmaf(w00, xr[j + 3], a0);
      a0 = fmaf(w01, xr[j + 4], a0);
      a0 = fmaf(w02, xr[j + 5], a0);
      a0 = fmaf(w03, xr[j + 6], a0);
      a1 = fmaf(w10, xr[j + 3], a1);
      a1 = fmaf(w11, xr[j + 4], a1);
      a1 = fmaf(w12, xr[j + 5], a1);
      a1 = fmaf(w13, xr[j + 6], a1);
      acc0[j] = a0; acc1[j] = a1;
    }
  }
  int d = d0 + (dp << 1);
  float cb0 = cb[d], cb1 = cb[d + 1];
  unsigned short* hb = h + (size_t)b * L_ * D_;
#pragma unroll
  for (int j = 0; j < 8; ++j) {
    int n = n0 + (seg << 3) + j;
    unsigned int pv = (unsigned int)f2bf(acc0[j] + cb0) |
                      ((unsigned int)f2bf(acc1[j] + cb1) << 16);
    *reinterpret_cast<unsigned int*>(&hb[(size_t)n * D_ + d]) = pv;
  }
}

// ---------------- Kernel 2a: u prep ----------------
__global__ __launch_bounds__(256) void k_uprep(
    const float* __restrict__ cw, const float* __restrict__ cb,
    const float* __restrict__ sw, float* __restrict__ us) {
  __shared__ float red[4][64];
  __shared__ float red2[64];
  int t = threadIdx.x;
  int p = t & 63, chunk = t >> 6;
  float s = 0.f;
  for (int d = chunk * 128; d < chunk * 128 + 128; ++d)
    s = fmaf(sw[d], cw[((size_t)d << 6) + p], s);
  red[chunk][p] = s;
  if (t < 64) {
    float pc = 0.f;
    for (int j = 0; j < 8; ++j) pc = fmaf(sw[t + 64 * j], cb[t + 64 * j], pc);
    red2[t] = pc;
  }
  __syncthreads();
  if (t < 64) us[t] = red[0][t] + red[1][t] + red[2][t] + red[3][t];
  if (t == 0) {
    float c0 = 0.f;
    for (int j = 0; j < 64; ++j) c0 += red2[j];
    us[64] = c0;
  }
}

// ---------------- Kernel 2b: scores -> softmax over m -> s0 (bf16) ----------------
__global__ __launch_bounds__(192) void k_scores(
    const float* __restrict__ x, const float* __restrict__ us,
    const float* __restrict__ sb, unsigned short* __restrict__ s0) {
  __shared__ float xs[DIN * 195];
  __shared__ float ul[65];
  __shared__ float tb[192];
  int bid = blockIdx.x;
  int b = bid / 22, blk = bid - b * 22;
  int base0 = blk * 192;
  int t = threadIdx.x;
  const float* xb = x + (size_t)b * DIN * L_;
  for (int q = t; q < DIN * 195; q += 192) {
    int i = q / 195, c = q - i * 195;
    int nx = base0 - 1 + c;
    xs[q] = (nx >= 0 && nx < L_) ? xb[i * L_ + nx] : 0.f;
  }
  if (t < 65) ul[t] = us[t];
  __syncthreads();
  int n = base0 + t;
  float tv = 0.f;
  if (n < L_) {
    tv = ul[64];
    for (int i = 0; i < DIN; ++i) {
#pragma unroll
      for (int k = 0; k < 4; ++k)
        tv = fmaf(xs[i * 195 + t + k], ul[(i << 2) + k], tv);
    }
  }
  tb[t] = tv;
  __syncthreads();
  if (n < NP) {
    float t1 = tb[t];
    int e2 = t & ~1;
    float t2 = 0.5f * (tb[e2] + tb[e2 + 1]);
    int e3 = (t / 3) * 3;
    float t3 = (1.f / 3.f) * (tb[e3] + tb[e3 + 1] + tb[e3 + 2]);
    int e4 = t & ~3;
    float t4 = 0.25f * (tb[e4] + tb[e4 + 1] + tb[e4 + 2] + tb[e4 + 3]);
    float sbv = sb[0];
    float c0s = t1 + sbv, c1s = t2 + sbv, c2s = t3 + sbv, c3s = t4 + sbv;
    float mx = fmaxf(fmaxf(c0s, c1s), fmaxf(c2s, c3s));
    float e0 = __expf(c0s - mx), e1 = __expf(c1s - mx);
    float e2f = __expf(c2s - mx), e3f = __expf(c3s - mx);
    float inv = 1.f / (e0 + e1 + e2f + e3f);
    ushort4 ov;
    ov.x = f2bf(e0 * inv); ov.y = f2bf(e1 * inv);
    ov.z = f2bf(e2f * inv); ov.w = f2bf(e3f * inv);
    *reinterpret_cast<ushort4*>(&s0[(((size_t)b * NP) + n) << 2]) = ov;
  }
}

// ---------------- Kernel 3: attention, 2 rows/thread, partial over j-slices ----------------
// grid: b(8) x ichunk(9) x jsplit(8). thread t owns rows i1=ic*512+t, i2=i1+256.
__global__ __launch_bounds__(256) void k_attn(
    const unsigned short* __restrict__ s0, float4* __restrict__ pa,
    float* __restrict__ pz) {
  __shared__ float4 sm[JS];
  int bid = blockIdx.x;
  int js = bid & 7;
  int ic = (bid >> 3) % 9;
  int b = bid / 72;
  int t = threadIdx.x;
  const ushort4* sp = reinterpret_cast<const ushort4*>(s0) + (size_t)b * NP;
  for (int q = t; q < JS; q += 256) {
    ushort4 u = sp[js * JS + q];
    float4 f;
    f.x = bf2f(u.x); f.y = bf2f(u.y); f.z = bf2f(u.z); f.w = bf2f(u.w);
    sm[q] = f;
  }
  __syncthreads();
  const float RLN2 = 1.44269504088896341f;  // log2(e)
  int i1 = ic * 512 + t;
  int i2 = i1 + 256;
  int i1c = (i1 < NP) ? i1 : (NP - 1);
  int i2c = (i2 < NP) ? i2 : (NP - 1);
  ushort4 u1 = sp[i1c], u2 = sp[i2c];
  float p0 = bf2f(u1.x) * RLN2, p1 = bf2f(u1.y) * RLN2;
  float p2 = bf2f(u1.z) * RLN2, p3 = bf2f(u1.w) * RLN2;
  float q0 = bf2f(u2.x) * RLN2, q1 = bf2f(u2.y) * RLN2;
  float q2 = bf2f(u2.z) * RLN2, q3 = bf2f(u2.w) * RLN2;
  float a0 = 0.f, a1 = 0.f, a2 = 0.f, a3 = 0.f, Z1 = 0.f;
  float b0 = 0.f, b1 = 0.f, b2 = 0.f, b3 = 0.f, Z2 = 0.f;
#pragma unroll 4
  for (int j = 0; j < JS; ++j) {
    float4 v = sm[j];
    float d1 = p0 * v.x;
    d1 = fmaf(p1, v.y, d1);
    d1 = fmaf(p2, v.z, d1);
    d1 = fmaf(p3, v.w, d1);
    float d2 = q0 * v.x;
    d2 = fmaf(q1, v.y, d2);
    d2 = fmaf(q2, v.z, d2);
    d2 = fmaf(q3, v.w, d2);
    float e1 = exp2f(d1);
    float e2 = exp2f(d2);
    a0 = fmaf(e1, v.x, a0);
    a1 = fmaf(e1, v.y, a1);
    a2 = fmaf(e1, v.z, a2);
    a3 = fmaf(e1, v.w, a3);
    Z1 += e1;
    b0 = fmaf(e2, v.x, b0);
    b1 = fmaf(e2, v.y, b1);
    b2 = fmaf(e2, v.z, b2);
    b3 = fmaf(e2, v.w, b3);
    Z2 += e2;
  }
  size_t pbase = ((size_t)(b * 8 + js)) * IPAD;
  if (i1 < NP) {
    pa[pbase + i1] = make_float4(a0, a1, a2, a3);
    pz[pbase + i1] = Z1;
  }
  if (i2 < NP) {
    pa[pbase + i2] = make_float4(b0, b1, b2, b3);
    pz[pbase + i2] = Z2;
  }
}

// ---------------- Kernel 3b: reduce partials -> s2 ----------------
__global__ __launch_bounds__(256) void k_attn_red(
    const float4* __restrict__ pa, const float* __restrict__ pz,
    float* __restrict__ s2) {
  int idx = blockIdx.x * 256 + threadIdx.x;
  if (idx >= B_ * NP) return;
  int b = idx / NP, i = idx - b * NP;
  float a0 = 0.f, a1 = 0.f, a2 = 0.f, a3 = 0.f, Z = 0.f;
#pragma unroll
  for (int js = 0; js < 8; ++js) {
    size_t p = ((size_t)(b * 8 + js)) * IPAD + i;
    float4 v = pa[p];
    a0 += v.x; a1 += v.y; a2 += v.z; a3 += v.w;
    Z += pz[p];
  }
  float inv = 1.f / Z;
  reinterpret_cast<float4*>(s2)[(size_t)b * NP + i] =
      make_float4(a0 * inv, a1 * inv, a2 * inv, a3 * inv);
}

// ---------------- Kernel 4: xo + outputs ----------------
__global__ __launch_bounds__(256) void k_final(
    const unsigned short* __restrict__ h, const float* __restrict__ s2,
    float* __restrict__ out) {
  __shared__ float ss[12][4];
  int bid = blockIdx.x;
  int b = bid / NG, g = bid - b * NG;
  int base = g * 12;
  int t = threadIdx.x;
  if (t < 48) ((float*)ss)[t] = s2[((((size_t)b * NP) + base) << 2) + t];
  __syncthreads();
  int d = t << 1;
  const unsigned short* hb = h + (size_t)b * L_ * D_;
  float hv0[12], hv1[12];
#pragma unroll
  for (int j = 0; j < 12; ++j) {
    int n = base + j;
    if (n < L_) {
      unsigned int u = *reinterpret_cast<const unsigned int*>(&hb[(size_t)n * D_ + d]);
      hv0[j] = bf2f(u & 0xffffu); hv1[j] = bf2f(u >> 16);
    } else { hv0[j] = 0.f; hv1[j] = 0.f; }
  }
  float P20[6], P21[6], P30[4], P31[4], P40[3], P41[3];
#pragma unroll
  for (int q = 0; q < 6; ++q) {
    P20[q] = 0.5f * (hv0[2 * q] + hv0[2 * q + 1]);
    P21[q] = 0.5f * (hv1[2 * q] + hv1[2 * q + 1]);
  }
#pragma unroll
  for (int q = 0; q < 4; ++q) {
    P30[q] = (1.f / 3.f) * (hv0[3 * q] + hv0[3 * q + 1] + hv0[3 * q + 2]);
    P31[q] = (1.f / 3.f) * (hv1[3 * q] + hv1[3 * q + 1] + hv1[3 * q + 2]);
  }
#pragma unroll
  for (int q = 0; q < 3; ++q) {
    P40[q] = 0.25f * (hv0[4 * q] + hv0[4 * q + 1] + hv0[4 * q + 2] + hv0[4 * q + 3]);
    P41[q] = 0.25f * (hv1[4 * q] + hv1[4 * q + 1] + hv1[4 * q + 2] + hv1[4 * q + 3]);
  }
  float* outc = out;
  float* outd = out + (size_t)B_ * L_ * D_;
  float xq0[3] = {0.f, 0.f, 0.f}, xq1[3] = {0.f, 0.f, 0.f};
#pragma unroll
  for (int j = 0; j < 12; ++j) {
    float w0 = ss[j][0], w1 = ss[j][1], w2 = ss[j][2], w3 = ss[j][3];
    float v0 = w0 * hv0[j] + w1 * P20[j >> 1] + w2 * P30[j / 3] + w3 * P40[j >> 2];
    float v1 = w0 * hv1[j] + w1 * P21[j >> 1] + w2 * P31[j / 3] + w3 * P41[j >> 2];
    int n = base + j;
    if (n < L_) {
      float2 o; o.x = v0; o.y = v1;
      *reinterpret_cast<float2*>(&outc[((size_t)b * L_ + n) * D_ + d]) = o;
    }
    xq0[j >> 2] += v0; xq1[j >> 2] += v1;
  }
#pragma unroll
  for (int q = 0; q < 3; ++q) {
    int r = 3 * g + q;
    if (r < 1024) {
      float2 o; o.x = 0.25f * xq0[q]; o.y = 0.25f * xq1[q];
      *reinterpret_cast<float2*>(&outd[((size_t)b * 1024 + r) * D_ + d]) = o;
    }
  }
}

extern "C" void kernel_launch(void* const* d_in, const int* in_sizes, int n_in,
                              void* d_out, int out_size, void* d_ws, size_t ws_size,
                              hipStream_t stream) {
  const float* x = (const float*)d_in[0];
  const float* cw = (const float*)d_in[1];
  const float* cb = (const float*)d_in[2];
  const float* sw = (const float*)d_in[3];
  const float* sb = (const float*)d_in[4];
  float* out = (float*)d_out;
  char* ws = (char*)d_ws;
  unsigned short* h = (unsigned short*)ws;                 // 33,554,432 B
  size_t off = 33554432;
  unsigned short* s0 = (unsigned short*)(ws + off);        // 262,656 B
  off += 262656;
  float* s2 = (float*)(ws + off);                          // 525,312 B
  off += 525312;
  float4* pa = (float4*)(ws + off);                        // 8*8*4352*16 = 4,456,448 B
  off += (size_t)B_ * 8 * IPAD * 16;
  float* pz = (float*)(ws + off);                          // 1,114,112 B
  off += (size_t)B_ * 8 * IPAD * 4;
  float* us = (float*)(ws + off);                          // 260 B

  k_conv<<<4096, 256, 0, stream>>>(x, cw, cb, h);
  k_uprep<<<1, 256, 0, stream>>>(cw, cb, sw, us);
  k_scores<<<8 * 22, 192, 0, stream>>>(x, us, sb, s0);
  k_attn<<<8 * 9 * 8, 256, 0, stream>>>(s0, pa, pz);
  k_attn_red<<<(B_ * NP + 255) / 256, 256, 0, stream>>>(pa, pz, s2);
  k_final<<<B_ * NG, 256, 0, stream>>>(h, s2, out);
}

// Round 4
// 138.623 us; speedup vs baseline: 1.1294x; 1.1294x over previous
//
#include <hip/hip_runtime.h>
#include <hip/hip_bf16.h>

#define B_ 8
#define DIN 16
#define L_ 4096
#define D_ 512
#define NP 4104
#define NG 342
#define JS 513
#define IPAD 4352

typedef float f32x2 __attribute__((ext_vector_type(2)));

__device__ __forceinline__ unsigned short f2bf(float f) {
  unsigned int u = __float_as_uint(f);
  unsigned int r = (u + 0x7fffu + ((u >> 16) & 1u)) >> 16;
  return (unsigned short)r;
}
__device__ __forceinline__ float bf2f(unsigned int u) {
  return __uint_as_float(u << 16);
}

// ---------------- Kernel 1: conv -> h (bf16) ----------------
__global__ __launch_bounds__(256) void k_conv(
    const float* __restrict__ x, const float* __restrict__ cw,
    const float* __restrict__ cb, unsigned short* __restrict__ h) {
  __shared__ float ws_w[64 * 132];
  __shared__ float ws_x[DIN * 40];
  int bid = blockIdx.x;
  int dtile = bid & 3;
  int ntile = (bid >> 2) & 127;
  int b = bid >> 9;
  int n0 = ntile * 32;
  int d0 = dtile * 128;
  int tid = threadIdx.x;

  for (int q = tid; q < 128 * 16; q += 256) {
    int dd = q >> 4, qq = (q & 15) << 2;
    float4 wv = *reinterpret_cast<const float4*>(cw + ((size_t)(d0 + dd) << 6) + qq);
    *reinterpret_cast<float4*>(&ws_w[(dd >> 1) * 132 + (dd & 1) * 64 + qq]) = wv;
  }
  const float* xb = x + (size_t)b * DIN * L_;
  for (int q = tid; q < DIN * 40; q += 256) {
    int i = q / 40, c = q - i * 40;
    int nx = n0 + c - 4;
    ws_x[q] = (nx >= 0 && nx < L_) ? xb[i * L_ + nx] : 0.0f;
  }
  __syncthreads();

  int dp = tid & 63;
  int seg = tid >> 6;
  float acc0[8], acc1[8];
#pragma unroll
  for (int j = 0; j < 8; ++j) { acc0[j] = 0.f; acc1[j] = 0.f; }

  for (int i = 0; i < DIN; ++i) {
    const float* wp = &ws_w[dp * 132 + (i << 2)];
    float w00 = wp[0], w01 = wp[1], w02 = wp[2], w03 = wp[3];
    float w10 = wp[64], w11 = wp[65], w12 = wp[66], w13 = wp[67];
    const float* xp = &ws_x[i * 40 + (seg << 3)];
    float xr[16];
#pragma unroll
    for (int m = 0; m < 16; ++m) xr[m] = xp[m];
#pragma unroll
    for (int j = 0; j < 8; ++j) {
      float a0 = acc0[j], a1 = acc1[j];
      a0 = fmaf(w00, xr[j + 3], a0);
      a0 = fmaf(w01, xr[j + 4], a0);
      a0 = fmaf(w02, xr[j + 5], a0);
      a0 = fmaf(w03, xr[j + 6], a0);
      a1 = fmaf(w10, xr[j + 3], a1);
      a1 = fmaf(w11, xr[j + 4], a1);
      a1 = fmaf(w12, xr[j + 5], a1);
      a1 = fmaf(w13, xr[j + 6], a1);
      acc0[j] = a0; acc1[j] = a1;
    }
  }
  int d = d0 + (dp << 1);
  float cb0 = cb[d], cb1 = cb[d + 1];
  unsigned short* hb = h + (size_t)b * L_ * D_;
#pragma unroll
  for (int j = 0; j < 8; ++j) {
    int n = n0 + (seg << 3) + j;
    unsigned int pv = (unsigned int)f2bf(acc0[j] + cb0) |
                      ((unsigned int)f2bf(acc1[j] + cb1) << 16);
    *reinterpret_cast<unsigned int*>(&hb[(size_t)n * D_ + d]) = pv;
  }
}

// ---------------- Kernel 2a: u prep ----------------
__global__ __launch_bounds__(256) void k_uprep(
    const float* __restrict__ cw, const float* __restrict__ cb,
    const float* __restrict__ sw, float* __restrict__ us) {
  __shared__ float red[4][64];
  __shared__ float red2[64];
  int t = threadIdx.x;
  int p = t & 63, chunk = t >> 6;
  float s = 0.f;
  for (int d = chunk * 128; d < chunk * 128 + 128; ++d)
    s = fmaf(sw[d], cw[((size_t)d << 6) + p], s);
  red[chunk][p] = s;
  if (t < 64) {
    float pc = 0.f;
    for (int j = 0; j < 8; ++j) pc = fmaf(sw[t + 64 * j], cb[t + 64 * j], pc);
    red2[t] = pc;
  }
  __syncthreads();
  if (t < 64) us[t] = red[0][t] + red[1][t] + red[2][t] + red[3][t];
  if (t == 0) {
    float c0 = 0.f;
    for (int j = 0; j < 64; ++j) c0 += red2[j];
    us[64] = c0;
  }
}

// ---------------- Kernel 2b: scores -> softmax over m -> s0 (bf16) ----------------
__global__ __launch_bounds__(192) void k_scores(
    const float* __restrict__ x, const float* __restrict__ us,
    const float* __restrict__ sb, unsigned short* __restrict__ s0) {
  __shared__ float xs[DIN * 195];
  __shared__ float ul[65];
  __shared__ float tb[192];
  int bid = blockIdx.x;
  int b = bid / 22, blk = bid - b * 22;
  int base0 = blk * 192;
  int t = threadIdx.x;
  const float* xb = x + (size_t)b * DIN * L_;
  for (int q = t; q < DIN * 195; q += 192) {
    int i = q / 195, c = q - i * 195;
    int nx = base0 - 1 + c;
    xs[q] = (nx >= 0 && nx < L_) ? xb[i * L_ + nx] : 0.f;
  }
  if (t < 65) ul[t] = us[t];
  __syncthreads();
  int n = base0 + t;
  float tv = 0.f;
  if (n < L_) {
    tv = ul[64];
    for (int i = 0; i < DIN; ++i) {
#pragma unroll
      for (int k = 0; k < 4; ++k)
        tv = fmaf(xs[i * 195 + t + k], ul[(i << 2) + k], tv);
    }
  }
  tb[t] = tv;
  __syncthreads();
  if (n < NP) {
    float t1 = tb[t];
    int e2 = t & ~1;
    float t2 = 0.5f * (tb[e2] + tb[e2 + 1]);
    int e3 = (t / 3) * 3;
    float t3 = (1.f / 3.f) * (tb[e3] + tb[e3 + 1] + tb[e3 + 2]);
    int e4 = t & ~3;
    float t4 = 0.25f * (tb[e4] + tb[e4 + 1] + tb[e4 + 2] + tb[e4 + 3]);
    float sbv = sb[0];
    float c0s = t1 + sbv, c1s = t2 + sbv, c2s = t3 + sbv, c3s = t4 + sbv;
    float mx = fmaxf(fmaxf(c0s, c1s), fmaxf(c2s, c3s));
    float e0 = __expf(c0s - mx), e1 = __expf(c1s - mx);
    float e2f = __expf(c2s - mx), e3f = __expf(c3s - mx);
    float inv = 1.f / (e0 + e1 + e2f + e3f);
    ushort4 ov;
    ov.x = f2bf(e0 * inv); ov.y = f2bf(e1 * inv);
    ov.z = f2bf(e2f * inv); ov.w = f2bf(e3f * inv);
    *reinterpret_cast<ushort4*>(&s0[(((size_t)b * NP) + n) << 2]) = ov;
  }
}

// ---------------- Kernel 3: attention, 1 row/thread, 128-thr blocks ----------------
// grid: b(8) x ichunk(33) x jsplit(8). thread t owns row i = ic*128+t.
__global__ __launch_bounds__(128) void k_attn(
    const unsigned short* __restrict__ s0, float4* __restrict__ pa,
    float* __restrict__ pz) {
  __shared__ float4 sm[JS];
  int bid = blockIdx.x;
  int js = bid & 7;
  int ic = (bid >> 3) % 33;
  int b = bid / 264;
  int t = threadIdx.x;
  const ushort4* sp = reinterpret_cast<const ushort4*>(s0) + (size_t)b * NP;
  for (int q = t; q < JS; q += 128) {
    ushort4 u = sp[js * JS + q];
    float4 f;
    f.x = bf2f(u.x); f.y = bf2f(u.y); f.z = bf2f(u.z); f.w = bf2f(u.w);
    sm[q] = f;
  }
  __syncthreads();
  const float RLN2 = 1.44269504088896341f;  // log2(e)
  int i = ic * 128 + t;
  int iw = (i < NP) ? i : (NP - 1);
  ushort4 su = sp[iw];
  f32x2 pxy, pzw;
  pxy.x = bf2f(su.x) * RLN2; pxy.y = bf2f(su.y) * RLN2;
  pzw.x = bf2f(su.z) * RLN2; pzw.y = bf2f(su.w) * RLN2;
  f32x2 axy = {0.f, 0.f}, azw = {0.f, 0.f};
  float Z = 0.f;
#pragma unroll 8
  for (int j = 0; j < JS; ++j) {
    float4 v = sm[j];
    f32x2 vxy, vzw;
    vxy.x = v.x; vxy.y = v.y; vzw.x = v.z; vzw.y = v.w;
    f32x2 tt = pxy * vxy + pzw * vzw;   // v_pk_mul + v_pk_fma
    float dt = tt.x + tt.y;
    float e = exp2f(dt);
    f32x2 ee = {e, e};
    axy += ee * vxy;                     // v_pk_fma
    azw += ee * vzw;                     // v_pk_fma
    Z += e;
  }
  if (i < NP) {
    size_t p = ((size_t)(b * 8 + js)) * IPAD + i;
    pa[p] = make_float4(axy.x, axy.y, azw.x, azw.y);
    pz[p] = Z;
  }
}

// ---------------- Kernel 3b: reduce partials -> s2 ----------------
__global__ __launch_bounds__(256) void k_attn_red(
    const float4* __restrict__ pa, const float* __restrict__ pz,
    float* __restrict__ s2) {
  int idx = blockIdx.x * 256 + threadIdx.x;
  if (idx >= B_ * NP) return;
  int b = idx / NP, i = idx - b * NP;
  float a0 = 0.f, a1 = 0.f, a2 = 0.f, a3 = 0.f, Z = 0.f;
#pragma unroll
  for (int js = 0; js < 8; ++js) {
    size_t p = ((size_t)(b * 8 + js)) * IPAD + i;
    float4 v = pa[p];
    a0 += v.x; a1 += v.y; a2 += v.z; a3 += v.w;
    Z += pz[p];
  }
  float inv = 1.f / Z;
  reinterpret_cast<float4*>(s2)[(size_t)b * NP + i] =
      make_float4(a0 * inv, a1 * inv, a2 * inv, a3 * inv);
}

// ---------------- Kernel 4: xo + outputs ----------------
__global__ __launch_bounds__(256) void k_final(
    const unsigned short* __restrict__ h, const float* __restrict__ s2,
    float* __restrict__ out) {
  __shared__ float ss[12][4];
  int bid = blockIdx.x;
  int b = bid / NG, g = bid - b * NG;
  int base = g * 12;
  int t = threadIdx.x;
  if (t < 48) ((float*)ss)[t] = s2[((((size_t)b * NP) + base) << 2) + t];
  __syncthreads();
  int d = t << 1;
  const unsigned short* hb = h + (size_t)b * L_ * D_;
  float hv0[12], hv1[12];
#pragma unroll
  for (int j = 0; j < 12; ++j) {
    int n = base + j;
    if (n < L_) {
      unsigned int u = *reinterpret_cast<const unsigned int*>(&hb[(size_t)n * D_ + d]);
      hv0[j] = bf2f(u & 0xffffu); hv1[j] = bf2f(u >> 16);
    } else { hv0[j] = 0.f; hv1[j] = 0.f; }
  }
  float P20[6], P21[6], P30[4], P31[4], P40[3], P41[3];
#pragma unroll
  for (int q = 0; q < 6; ++q) {
    P20[q] = 0.5f * (hv0[2 * q] + hv0[2 * q + 1]);
    P21[q] = 0.5f * (hv1[2 * q] + hv1[2 * q + 1]);
  }
#pragma unroll
  for (int q = 0; q < 4; ++q) {
    P30[q] = (1.f / 3.f) * (hv0[3 * q] + hv0[3 * q + 1] + hv0[3 * q + 2]);
    P31[q] = (1.f / 3.f) * (hv1[3 * q] + hv1[3 * q + 1] + hv1[3 * q + 2]);
  }
#pragma unroll
  for (int q = 0; q < 3; ++q) {
    P40[q] = 0.25f * (hv0[4 * q] + hv0[4 * q + 1] + hv0[4 * q + 2] + hv0[4 * q + 3]);
    P41[q] = 0.25f * (hv1[4 * q] + hv1[4 * q + 1] + hv1[4 * q + 2] + hv1[4 * q + 3]);
  }
  float* outc = out;
  float* outd = out + (size_t)B_ * L_ * D_;
  float xq0[3] = {0.f, 0.f, 0.f}, xq1[3] = {0.f, 0.f, 0.f};
#pragma unroll
  for (int j = 0; j < 12; ++j) {
    float w0 = ss[j][0], w1 = ss[j][1], w2 = ss[j][2], w3 = ss[j][3];
    float v0 = w0 * hv0[j] + w1 * P20[j >> 1] + w2 * P30[j / 3] + w3 * P40[j >> 2];
    float v1 = w0 * hv1[j] + w1 * P21[j >> 1] + w2 * P31[j / 3] + w3 * P41[j >> 2];
    int n = base + j;
    if (n < L_) {
      float2 o; o.x = v0; o.y = v1;
      *reinterpret_cast<float2*>(&outc[((size_t)b * L_ + n) * D_ + d]) = o;
    }
    xq0[j >> 2] += v0; xq1[j >> 2] += v1;
  }
#pragma unroll
  for (int q = 0; q < 3; ++q) {
    int r = 3 * g + q;
    if (r < 1024) {
      float2 o; o.x = 0.25f * xq0[q]; o.y = 0.25f * xq1[q];
      *reinterpret_cast<float2*>(&outd[((size_t)b * 1024 + r) * D_ + d]) = o;
    }
  }
}

extern "C" void kernel_launch(void* const* d_in, const int* in_sizes, int n_in,
                              void* d_out, int out_size, void* d_ws, size_t ws_size,
                              hipStream_t stream) {
  const float* x = (const float*)d_in[0];
  const float* cw = (const float*)d_in[1];
  const float* cb = (const float*)d_in[2];
  const float* sw = (const float*)d_in[3];
  const float* sb = (const float*)d_in[4];
  float* out = (float*)d_out;
  char* ws = (char*)d_ws;
  unsigned short* h = (unsigned short*)ws;                 // 33,554,432 B
  size_t off = 33554432;
  unsigned short* s0 = (unsigned short*)(ws + off);        // 262,656 B
  off += 262656;
  float* s2 = (float*)(ws + off);                          // 525,312 B
  off += 525312;
  float4* pa = (float4*)(ws + off);                        // 8*8*4352*16 = 4,456,448 B
  off += (size_t)B_ * 8 * IPAD * 16;
  float* pz = (float*)(ws + off);                          // 1,114,112 B
  off += (size_t)B_ * 8 * IPAD * 4;
  float* us = (float*)(ws + off);                          // 260 B

  k_conv<<<4096, 256, 0, stream>>>(x, cw, cb, h);
  k_uprep<<<1, 256, 0, stream>>>(cw, cb, sw, us);
  k_scores<<<8 * 22, 192, 0, stream>>>(x, us, sb, s0);
  k_attn<<<8 * 33 * 8, 128, 0, stream>>>(s0, pa, pz);
  k_attn_red<<<(B_ * NP + 255) / 256, 256, 0, stream>>>(pa, pz, s2);
  k_final<<<B_ * NG, 256, 0, stream>>>(h, s2, out);
}

// Round 5
// 92.441 us; speedup vs baseline: 1.6937x; 1.4996x over previous
//
#include <hip/hip_runtime.h>
#include <hip/hip_bf16.h>

#define B_ 8
#define DIN 16
#define L_ 4096
#define D_ 512
#define NP 4104
#define NG 342
#define JSP 32
#define JCH 129

__device__ __forceinline__ unsigned short f2bf(float f) {
  unsigned int u = __float_as_uint(f);
  unsigned int r = (u + 0x7fffu + ((u >> 16) & 1u)) >> 16;
  return (unsigned short)r;
}
__device__ __forceinline__ float bf2f(unsigned int u) {
  return __uint_as_float(u << 16);
}

// degree-5 Taylor of e^t about t0=0.525, raw monomial basis; valid [0,1.05], err<=1e-4
__device__ __constant__ float D5[6] = {0.9999544f, 1.0005163f, 0.4975827f,
                                       0.1726558f, 0.0334570f, 0.0140872f};
__device__ __constant__ float FACT[6] = {1.f, 1.f, 2.f, 6.f, 24.f, 120.f};

// ---------------- Kernel 1: conv -> h (bf16) ----------------
__global__ __launch_bounds__(256) void k_conv(
    const float* __restrict__ x, const float* __restrict__ cw,
    const float* __restrict__ cb, unsigned short* __restrict__ h) {
  __shared__ float ws_w[64 * 132];
  __shared__ float ws_x[DIN * 40];
  int bid = blockIdx.x;
  int dtile = bid & 3;
  int ntile = (bid >> 2) & 127;
  int b = bid >> 9;
  int n0 = ntile * 32;
  int d0 = dtile * 128;
  int tid = threadIdx.x;

  for (int q = tid; q < 128 * 16; q += 256) {
    int dd = q >> 4, qq = (q & 15) << 2;
    float4 wv = *reinterpret_cast<const float4*>(cw + ((size_t)(d0 + dd) << 6) + qq);
    *reinterpret_cast<float4*>(&ws_w[(dd >> 1) * 132 + (dd & 1) * 64 + qq]) = wv;
  }
  const float* xb = x + (size_t)b * DIN * L_;
  for (int q = tid; q < DIN * 40; q += 256) {
    int i = q / 40, c = q - i * 40;
    int nx = n0 + c - 4;
    ws_x[q] = (nx >= 0 && nx < L_) ? xb[i * L_ + nx] : 0.0f;
  }
  __syncthreads();

  int dp = tid & 63;
  int seg = tid >> 6;
  float acc0[8], acc1[8];
#pragma unroll
  for (int j = 0; j < 8; ++j) { acc0[j] = 0.f; acc1[j] = 0.f; }

  for (int i = 0; i < DIN; ++i) {
    const float* wp = &ws_w[dp * 132 + (i << 2)];
    float w00 = wp[0], w01 = wp[1], w02 = wp[2], w03 = wp[3];
    float w10 = wp[64], w11 = wp[65], w12 = wp[66], w13 = wp[67];
    const float* xp = &ws_x[i * 40 + (seg << 3)];
    float xr[16];
#pragma unroll
    for (int m = 0; m < 16; ++m) xr[m] = xp[m];
#pragma unroll
    for (int j = 0; j < 8; ++j) {
      float a0 = acc0[j], a1 = acc1[j];
      a0 = fmaf(w00, xr[j + 3], a0);
      a0 = fmaf(w01, xr[j + 4], a0);
      a0 = fmaf(w02, xr[j + 5], a0);
      a0 = fmaf(w03, xr[j + 6], a0);
      a1 = fmaf(w10, xr[j + 3], a1);
      a1 = fmaf(w11, xr[j + 4], a1);
      a1 = fmaf(w12, xr[j + 5], a1);
      a1 = fmaf(w13, xr[j + 6], a1);
      acc0[j] = a0; acc1[j] = a1;
    }
  }
  int d = d0 + (dp << 1);
  float cb0 = cb[d], cb1 = cb[d + 1];
  unsigned short* hb = h + (size_t)b * L_ * D_;
#pragma unroll
  for (int j = 0; j < 8; ++j) {
    int n = n0 + (seg << 3) + j;
    unsigned int pv = (unsigned int)f2bf(acc0[j] + cb0) |
                      ((unsigned int)f2bf(acc1[j] + cb1) << 16);
    *reinterpret_cast<unsigned int*>(&hb[(size_t)n * D_ + d]) = pv;
  }
}

// ---------------- Kernel 2a: u prep ----------------
__global__ __launch_bounds__(256) void k_uprep(
    const float* __restrict__ cw, const float* __restrict__ cb,
    const float* __restrict__ sw, float* __restrict__ us) {
  __shared__ float red[4][64];
  __shared__ float red2[64];
  int t = threadIdx.x;
  int p = t & 63, chunk = t >> 6;
  float s = 0.f;
  for (int d = chunk * 128; d < chunk * 128 + 128; ++d)
    s = fmaf(sw[d], cw[((size_t)d << 6) + p], s);
  red[chunk][p] = s;
  if (t < 64) {
    float pc = 0.f;
    for (int j = 0; j < 8; ++j) pc = fmaf(sw[t + 64 * j], cb[t + 64 * j], pc);
    red2[t] = pc;
  }
  __syncthreads();
  if (t < 64) us[t] = red[0][t] + red[1][t] + red[2][t] + red[3][t];
  if (t == 0) {
    float c0 = 0.f;
    for (int j = 0; j < 64; ++j) c0 += red2[j];
    us[64] = c0;
  }
}

// ---------------- Kernel 2b: scores -> softmax over m -> s0 (bf16) ----------------
__global__ __launch_bounds__(192) void k_scores(
    const float* __restrict__ x, const float* __restrict__ us,
    const float* __restrict__ sb, unsigned short* __restrict__ s0) {
  __shared__ float xs[DIN * 195];
  __shared__ float ul[65];
  __shared__ float tb[192];
  int bid = blockIdx.x;
  int b = bid / 22, blk = bid - b * 22;
  int base0 = blk * 192;
  int t = threadIdx.x;
  const float* xb = x + (size_t)b * DIN * L_;
  for (int q = t; q < DIN * 195; q += 192) {
    int i = q / 195, c = q - i * 195;
    int nx = base0 - 1 + c;
    xs[q] = (nx >= 0 && nx < L_) ? xb[i * L_ + nx] : 0.f;
  }
  if (t < 65) ul[t] = us[t];
  __syncthreads();
  int n = base0 + t;
  float tv = 0.f;
  if (n < L_) {
    tv = ul[64];
    for (int i = 0; i < DIN; ++i) {
#pragma unroll
      for (int k = 0; k < 4; ++k)
        tv = fmaf(xs[i * 195 + t + k], ul[(i << 2) + k], tv);
    }
  }
  tb[t] = tv;
  __syncthreads();
  if (n < NP) {
    float t1 = tb[t];
    int e2 = t & ~1;
    float t2 = 0.5f * (tb[e2] + tb[e2 + 1]);
    int e3 = (t / 3) * 3;
    float t3 = (1.f / 3.f) * (tb[e3] + tb[e3 + 1] + tb[e3 + 2]);
    int e4 = t & ~3;
    float t4 = 0.25f * (tb[e4] + tb[e4 + 1] + tb[e4 + 2] + tb[e4 + 3]);
    float sbv = sb[0];
    float c0s = t1 + sbv, c1s = t2 + sbv, c2s = t3 + sbv, c3s = t4 + sbv;
    float mx = fmaxf(fmaxf(c0s, c1s), fmaxf(c2s, c3s));
    float e0 = __expf(c0s - mx), e1 = __expf(c1s - mx);
    float e2f = __expf(c2s - mx), e3f = __expf(c3s - mx);
    float inv = 1.f / (e0 + e1 + e2f + e3f);
    ushort4 ov;
    ov.x = f2bf(e0 * inv); ov.y = f2bf(e1 * inv);
    ov.z = f2bf(e2f * inv); ov.w = f2bf(e3f * inv);
    *reinterpret_cast<ushort4*>(&s0[(((size_t)b * NP) + n) << 2]) = ov;
  }
}

// ---------------- Kernel 3a: moment accumulation ----------------
// grid: b(8) x jsplit(32); block 256 = 4 waves. lane owns features (lane, lane+64).
// Mpart[(b*32+js)*640 + f*5+c] = sum_{j in slice} s_j^alpha(f) * [s_j, 1][c]
__global__ __launch_bounds__(256) void k_moment(
    const unsigned short* __restrict__ s0, float* __restrict__ Mpart) {
  __shared__ float sv[JCH][4];
  __shared__ float ls[JCH][4];
  __shared__ float mp[4][128][5];
  int bid = blockIdx.x;
  int js = bid & 31;
  int b = bid >> 5;
  int t = threadIdx.x;
  int lane = t & 63, wv = t >> 6;
  int jlo = js * JCH;
  int cnt = NP - jlo; if (cnt > JCH) cnt = JCH;

  const ushort4* sp = reinterpret_cast<const ushort4*>(s0) + (size_t)b * NP + jlo;
  for (int r = t; r < cnt; r += 256) {
    ushort4 u = sp[r];
    float v0 = bf2f(u.x), v1 = bf2f(u.y), v2 = bf2f(u.z), v3 = bf2f(u.w);
    sv[r][0] = v0; sv[r][1] = v1; sv[r][2] = v2; sv[r][3] = v3;
    ls[r][0] = __log2f(v0); ls[r][1] = __log2f(v1);
    ls[r][2] = __log2f(v2); ls[r][3] = __log2f(v3);
  }
  // decode this lane's two feature exponent vectors
  int f1 = lane, f2 = lane + 64;
  float e1a = 0.f, e1b = 0.f, e1c = 0.f, e1d = 0.f;
  float e2a = 0.f, e2b = 0.f, e2c = 0.f, e2d = 0.f;
  {
    int f = 0;
    for (int a = 0; a <= 5; ++a)
      for (int b2 = 0; b2 <= 5 - a; ++b2)
        for (int c = 0; c <= 5 - a - b2; ++c)
          for (int d2 = 0; d2 <= 5 - a - b2 - c; ++d2) {
            if (f == f1) { e1a = a; e1b = b2; e1c = c; e1d = d2; }
            if (f == f2) { e2a = a; e2b = b2; e2c = c; e2d = d2; }
            ++f;
          }
  }
  __syncthreads();
  float acc1[5] = {0.f, 0.f, 0.f, 0.f, 0.f};
  float acc2[5] = {0.f, 0.f, 0.f, 0.f, 0.f};
  for (int jj = wv; jj < cnt; jj += 4) {
    float4 lv = *reinterpret_cast<float4*>(&ls[jj][0]);
    float4 vv = *reinterpret_cast<float4*>(&sv[jj][0]);
    float t1 = e1a * lv.x;
    t1 = fmaf(e1b, lv.y, t1);
    t1 = fmaf(e1c, lv.z, t1);
    t1 = fmaf(e1d, lv.w, t1);
    float t2 = e2a * lv.x;
    t2 = fmaf(e2b, lv.y, t2);
    t2 = fmaf(e2c, lv.z, t2);
    t2 = fmaf(e2d, lv.w, t2);
    float m1 = exp2f(t1);
    float m2 = exp2f(t2);
    acc1[0] = fmaf(m1, vv.x, acc1[0]);
    acc1[1] = fmaf(m1, vv.y, acc1[1]);
    acc1[2] = fmaf(m1, vv.z, acc1[2]);
    acc1[3] = fmaf(m1, vv.w, acc1[3]);
    acc1[4] += m1;
    acc2[0] = fmaf(m2, vv.x, acc2[0]);
    acc2[1] = fmaf(m2, vv.y, acc2[1]);
    acc2[2] = fmaf(m2, vv.z, acc2[2]);
    acc2[3] = fmaf(m2, vv.w, acc2[3]);
    acc2[4] += m2;
  }
#pragma unroll
  for (int c = 0; c < 5; ++c) {
    mp[wv][lane][c] = acc1[c];
    mp[wv][lane + 64][c] = acc2[c];
  }
  __syncthreads();
  if (t < 630) {
    int f = t / 5, c = t - f * 5;
    float s = mp[0][f][c] + mp[1][f][c] + mp[2][f][c] + mp[3][f][c];
    Mpart[((size_t)(b * 32 + js)) * 640 + t] = s;
  }
}

// ---------------- Kernel 3b: reduce partials, fold weights -> Mfin[b][128][8] ----------------
__global__ __launch_bounds__(640) void k_mred(
    const float* __restrict__ Mpart, float* __restrict__ Mfin) {
  int b = blockIdx.x;
  int t = threadIdx.x;
  if (t >= 630) return;
  int f = t / 5, c = t - f * 5;
  float s = 0.f;
  for (int js = 0; js < JSP; ++js)
    s += Mpart[((size_t)(b * 32 + js)) * 640 + t];
  // decode f -> (a,b2,cc,d2) and weight
  int fa = 0, fb = 0, fc = 0, fd = 0;
  {
    int ff = 0;
    for (int a = 0; a <= 5; ++a)
      for (int b2 = 0; b2 <= 5 - a; ++b2)
        for (int cc = 0; cc <= 5 - a - b2; ++cc)
          for (int d2 = 0; d2 <= 5 - a - b2 - cc; ++d2) {
            if (ff == f) { fa = a; fb = b2; fc = cc; fd = d2; }
            ++ff;
          }
  }
  int k = fa + fb + fc + fd;
  float w = D5[k] * FACT[k] / (FACT[fa] * FACT[fb] * FACT[fc] * FACT[fd]);
  Mfin[((size_t)b * 128 + f) * 8 + c] = w * s;
}

// ---------------- Kernel 3c: apply -> s2[b][i][4] ----------------
__global__ __launch_bounds__(256) void k_apply(
    const unsigned short* __restrict__ s0, const float* __restrict__ Mfin,
    float* __restrict__ s2) {
  __shared__ float M[128 * 8];
  int bid = blockIdx.x;
  int b = bid / 17, ch = bid - b * 17;
  int t = threadIdx.x;
  const float4* Mb = reinterpret_cast<const float4*>(Mfin + (size_t)b * 128 * 8);
  if (t < 252) *reinterpret_cast<float4*>(&M[t * 4]) = Mb[t];
  __syncthreads();
  int i = ch * 256 + t;
  if (i >= NP) return;
  ushort4 u = reinterpret_cast<const ushort4*>(s0)[(size_t)b * NP + i];
  float s_0 = bf2f(u.x), s_1 = bf2f(u.y), s_2 = bf2f(u.z), s_3 = bf2f(u.w);
  float a0 = 0.f, a1 = 0.f, a2 = 0.f, a3 = 0.f, az = 0.f;
  int f = 0;
  float pa = 1.f;
#pragma unroll
  for (int a = 0; a <= 5; ++a) {
    float pb = pa;
#pragma unroll
    for (int b2 = 0; b2 <= 5 - a; ++b2) {
      float pc = pb;
#pragma unroll
      for (int c = 0; c <= 5 - a - b2; ++c) {
        float run = pc;
#pragma unroll
        for (int d2 = 0; d2 <= 5 - a - b2 - c; ++d2) {
          const float* mf = &M[f * 8];
          float4 m4 = *reinterpret_cast<const float4*>(mf);
          a0 = fmaf(run, m4.x, a0);
          a1 = fmaf(run, m4.y, a1);
          a2 = fmaf(run, m4.z, a2);
          a3 = fmaf(run, m4.w, a3);
          az = fmaf(run, mf[4], az);
          run *= s_3;
          ++f;
        }
        pc *= s_2;
      }
      pb *= s_1;
    }
    pa *= s_0;
  }
  float inv = 1.f / az;
  reinterpret_cast<float4*>(s2)[(size_t)b * NP + i] =
      make_float4(a0 * inv, a1 * inv, a2 * inv, a3 * inv);
}

// ---------------- Kernel 4: xo + outputs ----------------
__global__ __launch_bounds__(256) void k_final(
    const unsigned short* __restrict__ h, const float* __restrict__ s2,
    float* __restrict__ out) {
  __shared__ float ss[12][4];
  int bid = blockIdx.x;
  int b = bid / NG, g = bid - b * NG;
  int base = g * 12;
  int t = threadIdx.x;
  if (t < 48) ((float*)ss)[t] = s2[((((size_t)b * NP) + base) << 2) + t];
  __syncthreads();
  int d = t << 1;
  const unsigned short* hb = h + (size_t)b * L_ * D_;
  float hv0[12], hv1[12];
#pragma unroll
  for (int j = 0; j < 12; ++j) {
    int n = base + j;
    if (n < L_) {
      unsigned int u = *reinterpret_cast<const unsigned int*>(&hb[(size_t)n * D_ + d]);
      hv0[j] = bf2f(u & 0xffffu); hv1[j] = bf2f(u >> 16);
    } else { hv0[j] = 0.f; hv1[j] = 0.f; }
  }
  float P20[6], P21[6], P30[4], P31[4], P40[3], P41[3];
#pragma unroll
  for (int q = 0; q < 6; ++q) {
    P20[q] = 0.5f * (hv0[2 * q] + hv0[2 * q + 1]);
    P21[q] = 0.5f * (hv1[2 * q] + hv1[2 * q + 1]);
  }
#pragma unroll
  for (int q = 0; q < 4; ++q) {
    P30[q] = (1.f / 3.f) * (hv0[3 * q] + hv0[3 * q + 1] + hv0[3 * q + 2]);
    P31[q] = (1.f / 3.f) * (hv1[3 * q] + hv1[3 * q + 1] + hv1[3 * q + 2]);
  }
#pragma unroll
  for (int q = 0; q < 3; ++q) {
    P40[q] = 0.25f * (hv0[4 * q] + hv0[4 * q + 1] + hv0[4 * q + 2] + hv0[4 * q + 3]);
    P41[q] = 0.25f * (hv1[4 * q] + hv1[4 * q + 1] + hv1[4 * q + 2] + hv1[4 * q + 3]);
  }
  float* outc = out;
  float* outd = out + (size_t)B_ * L_ * D_;
  float xq0[3] = {0.f, 0.f, 0.f}, xq1[3] = {0.f, 0.f, 0.f};
#pragma unroll
  for (int j = 0; j < 12; ++j) {
    float w0 = ss[j][0], w1 = ss[j][1], w2 = ss[j][2], w3 = ss[j][3];
    float v0 = w0 * hv0[j] + w1 * P20[j >> 1] + w2 * P30[j / 3] + w3 * P40[j >> 2];
    float v1 = w0 * hv1[j] + w1 * P21[j >> 1] + w2 * P31[j / 3] + w3 * P41[j >> 2];
    int n = base + j;
    if (n < L_) {
      float2 o; o.x = v0; o.y = v1;
      *reinterpret_cast<float2*>(&outc[((size_t)b * L_ + n) * D_ + d]) = o;
    }
    xq0[j >> 2] += v0; xq1[j >> 2] += v1;
  }
#pragma unroll
  for (int q = 0; q < 3; ++q) {
    int r = 3 * g + q;
    if (r < 1024) {
      float2 o; o.x = 0.25f * xq0[q]; o.y = 0.25f * xq1[q];
      *reinterpret_cast<float2*>(&outd[((size_t)b * 1024 + r) * D_ + d]) = o;
    }
  }
}

extern "C" void kernel_launch(void* const* d_in, const int* in_sizes, int n_in,
                              void* d_out, int out_size, void* d_ws, size_t ws_size,
                              hipStream_t stream) {
  const float* x = (const float*)d_in[0];
  const float* cw = (const float*)d_in[1];
  const float* cb = (const float*)d_in[2];
  const float* sw = (const float*)d_in[3];
  const float* sb = (const float*)d_in[4];
  float* out = (float*)d_out;
  char* ws = (char*)d_ws;
  unsigned short* h = (unsigned short*)ws;                 // 33,554,432 B
  size_t off = 33554432;
  unsigned short* s0 = (unsigned short*)(ws + off);        // 262,656 B
  off += 262656;
  float* s2 = (float*)(ws + off);                          // 525,312 B
  off += 525312;
  float* Mpart = (float*)(ws + off);                       // 8*32*640*4 = 655,360 B
  off += 655360;
  float* Mfin = (float*)(ws + off);                        // 8*128*8*4 = 32,768 B
  off += 32768;
  float* us = (float*)(ws + off);                          // 260 B

  k_conv<<<4096, 256, 0, stream>>>(x, cw, cb, h);
  k_uprep<<<1, 256, 0, stream>>>(cw, cb, sw, us);
  k_scores<<<8 * 22, 192, 0, stream>>>(x, us, sb, s0);
  k_moment<<<B_ * JSP, 256, 0, stream>>>(s0, Mpart);
  k_mred<<<B_, 640, 0, stream>>>(Mpart, Mfin);
  k_apply<<<B_ * 17, 256, 0, stream>>>(s0, Mfin, s2);
  k_final<<<B_ * NG, 256, 0, stream>>>(h, s2, out);
}

// Round 6
// 76.834 us; speedup vs baseline: 2.0377x; 1.2031x over previous
//
#include <hip/hip_runtime.h>
#include <hip/hip_bf16.h>

#define B_ 8
#define DIN 16
#define L_ 4096
#define D_ 512
#define NP 4104
#define NG 342
#define JSP 32
#define JCH 129
#define SPAN 48
#define NSPAN 86

__device__ __forceinline__ unsigned short f2bf(float f) {
  unsigned int u = __float_as_uint(f);
  unsigned int r = (u + 0x7fffu + ((u >> 16) & 1u)) >> 16;
  return (unsigned short)r;
}
__device__ __forceinline__ float bf2f(unsigned int u) {
  return __uint_as_float(u << 16);
}

// degree-5 Taylor of e^t about t0=0.525, raw monomial basis; valid [0,1.05], err<=1e-4
__device__ __constant__ float D5[6] = {0.9999544f, 1.0005163f, 0.4975827f,
                                       0.1726558f, 0.0334570f, 0.0140872f};
__device__ __constant__ float FACT[6] = {1.f, 1.f, 2.f, 6.f, 24.f, 120.f};

// ---------------- Kernel 2a: u prep ----------------
__global__ __launch_bounds__(256) void k_uprep(
    const float* __restrict__ cw, const float* __restrict__ cb,
    const float* __restrict__ sw, float* __restrict__ us) {
  __shared__ float red[4][64];
  __shared__ float red2[64];
  int t = threadIdx.x;
  int p = t & 63, chunk = t >> 6;
  float s = 0.f;
  for (int d = chunk * 128; d < chunk * 128 + 128; ++d)
    s = fmaf(sw[d], cw[((size_t)d << 6) + p], s);
  red[chunk][p] = s;
  if (t < 64) {
    float pc = 0.f;
    for (int j = 0; j < 8; ++j) pc = fmaf(sw[t + 64 * j], cb[t + 64 * j], pc);
    red2[t] = pc;
  }
  __syncthreads();
  if (t < 64) us[t] = red[0][t] + red[1][t] + red[2][t] + red[3][t];
  if (t == 0) {
    float c0 = 0.f;
    for (int j = 0; j < 64; ++j) c0 += red2[j];
    us[64] = c0;
  }
}

// ---------------- Kernel 2b: scores -> softmax over m -> s0 (bf16) ----------------
__global__ __launch_bounds__(192) void k_scores(
    const float* __restrict__ x, const float* __restrict__ us,
    const float* __restrict__ sb, unsigned short* __restrict__ s0) {
  __shared__ float xs[DIN * 195];
  __shared__ float ul[65];
  __shared__ float tb[192];
  int bid = blockIdx.x;
  int b = bid / 22, blk = bid - b * 22;
  int base0 = blk * 192;
  int t = threadIdx.x;
  const float* xb = x + (size_t)b * DIN * L_;
  for (int q = t; q < DIN * 195; q += 192) {
    int i = q / 195, c = q - i * 195;
    int nx = base0 - 1 + c;
    xs[q] = (nx >= 0 && nx < L_) ? xb[i * L_ + nx] : 0.f;
  }
  if (t < 65) ul[t] = us[t];
  __syncthreads();
  int n = base0 + t;
  float tv = 0.f;
  if (n < L_) {
    tv = ul[64];
    for (int i = 0; i < DIN; ++i) {
#pragma unroll
      for (int k = 0; k < 4; ++k)
        tv = fmaf(xs[i * 195 + t + k], ul[(i << 2) + k], tv);
    }
  }
  tb[t] = tv;
  __syncthreads();
  if (n < NP) {
    float t1 = tb[t];
    int e2 = t & ~1;
    float t2 = 0.5f * (tb[e2] + tb[e2 + 1]);
    int e3 = (t / 3) * 3;
    float t3 = (1.f / 3.f) * (tb[e3] + tb[e3 + 1] + tb[e3 + 2]);
    int e4 = t & ~3;
    float t4 = 0.25f * (tb[e4] + tb[e4 + 1] + tb[e4 + 2] + tb[e4 + 3]);
    float sbv = sb[0];
    float c0s = t1 + sbv, c1s = t2 + sbv, c2s = t3 + sbv, c3s = t4 + sbv;
    float mx = fmaxf(fmaxf(c0s, c1s), fmaxf(c2s, c3s));
    float e0 = __expf(c0s - mx), e1 = __expf(c1s - mx);
    float e2f = __expf(c2s - mx), e3f = __expf(c3s - mx);
    float inv = 1.f / (e0 + e1 + e2f + e3f);
    ushort4 ov;
    ov.x = f2bf(e0 * inv); ov.y = f2bf(e1 * inv);
    ov.z = f2bf(e2f * inv); ov.w = f2bf(e3f * inv);
    *reinterpret_cast<ushort4*>(&s0[(((size_t)b * NP) + n) << 2]) = ov;
  }
}

// ---------------- Kernel 3a: moment accumulation ----------------
__global__ __launch_bounds__(256) void k_moment(
    const unsigned short* __restrict__ s0, float* __restrict__ Mpart) {
  __shared__ float sv[JCH][4];
  __shared__ float ls[JCH][4];
  __shared__ float mp[4][128][5];
  int bid = blockIdx.x;
  int js = bid & 31;
  int b = bid >> 5;
  int t = threadIdx.x;
  int lane = t & 63, wv = t >> 6;
  int jlo = js * JCH;
  int cnt = NP - jlo; if (cnt > JCH) cnt = JCH;

  const ushort4* sp = reinterpret_cast<const ushort4*>(s0) + (size_t)b * NP + jlo;
  for (int r = t; r < cnt; r += 256) {
    ushort4 u = sp[r];
    float v0 = bf2f(u.x), v1 = bf2f(u.y), v2 = bf2f(u.z), v3 = bf2f(u.w);
    sv[r][0] = v0; sv[r][1] = v1; sv[r][2] = v2; sv[r][3] = v3;
    ls[r][0] = __log2f(v0); ls[r][1] = __log2f(v1);
    ls[r][2] = __log2f(v2); ls[r][3] = __log2f(v3);
  }
  int f1 = lane, f2 = lane + 64;
  float e1a = 0.f, e1b = 0.f, e1c = 0.f, e1d = 0.f;
  float e2a = 0.f, e2b = 0.f, e2c = 0.f, e2d = 0.f;
  {
    int f = 0;
    for (int a = 0; a <= 5; ++a)
      for (int b2 = 0; b2 <= 5 - a; ++b2)
        for (int c = 0; c <= 5 - a - b2; ++c)
          for (int d2 = 0; d2 <= 5 - a - b2 - c; ++d2) {
            if (f == f1) { e1a = a; e1b = b2; e1c = c; e1d = d2; }
            if (f == f2) { e2a = a; e2b = b2; e2c = c; e2d = d2; }
            ++f;
          }
  }
  __syncthreads();
  float acc1[5] = {0.f, 0.f, 0.f, 0.f, 0.f};
  float acc2[5] = {0.f, 0.f, 0.f, 0.f, 0.f};
  for (int jj = wv; jj < cnt; jj += 4) {
    float4 lv = *reinterpret_cast<float4*>(&ls[jj][0]);
    float4 vv = *reinterpret_cast<float4*>(&sv[jj][0]);
    float t1 = e1a * lv.x;
    t1 = fmaf(e1b, lv.y, t1);
    t1 = fmaf(e1c, lv.z, t1);
    t1 = fmaf(e1d, lv.w, t1);
    float t2 = e2a * lv.x;
    t2 = fmaf(e2b, lv.y, t2);
    t2 = fmaf(e2c, lv.z, t2);
    t2 = fmaf(e2d, lv.w, t2);
    float m1 = exp2f(t1);
    float m2 = exp2f(t2);
    acc1[0] = fmaf(m1, vv.x, acc1[0]);
    acc1[1] = fmaf(m1, vv.y, acc1[1]);
    acc1[2] = fmaf(m1, vv.z, acc1[2]);
    acc1[3] = fmaf(m1, vv.w, acc1[3]);
    acc1[4] += m1;
    acc2[0] = fmaf(m2, vv.x, acc2[0]);
    acc2[1] = fmaf(m2, vv.y, acc2[1]);
    acc2[2] = fmaf(m2, vv.z, acc2[2]);
    acc2[3] = fmaf(m2, vv.w, acc2[3]);
    acc2[4] += m2;
  }
#pragma unroll
  for (int c = 0; c < 5; ++c) {
    mp[wv][lane][c] = acc1[c];
    mp[wv][lane + 64][c] = acc2[c];
  }
  __syncthreads();
  if (t < 630) {
    int f = t / 5, c = t - f * 5;
    float s = mp[0][f][c] + mp[1][f][c] + mp[2][f][c] + mp[3][f][c];
    Mpart[((size_t)(b * 32 + js)) * 640 + t] = s;
  }
}

// ---------------- Kernel 3b: reduce partials, fold weights -> Mfin[b][128][8] ----------------
__global__ __launch_bounds__(640) void k_mred(
    const float* __restrict__ Mpart, float* __restrict__ Mfin) {
  int b = blockIdx.x;
  int t = threadIdx.x;
  if (t >= 630) return;
  int f = t / 5, c = t - f * 5;
  float s = 0.f;
  for (int js = 0; js < JSP; ++js)
    s += Mpart[((size_t)(b * 32 + js)) * 640 + t];
  int fa = 0, fb = 0, fc = 0, fd = 0;
  {
    int ff = 0;
    for (int a = 0; a <= 5; ++a)
      for (int b2 = 0; b2 <= 5 - a; ++b2)
        for (int cc = 0; cc <= 5 - a - b2; ++cc)
          for (int d2 = 0; d2 <= 5 - a - b2 - cc; ++d2) {
            if (ff == f) { fa = a; fb = b2; fc = cc; fd = d2; }
            ++ff;
          }
  }
  int k = fa + fb + fc + fd;
  float w = D5[k] * FACT[k] / (FACT[fa] * FACT[fb] * FACT[fc] * FACT[fd]);
  Mfin[((size_t)b * 128 + f) * 8 + c] = w * s;
}

// ---------------- Kernel 3c: apply -> s2[b][i][4] ----------------
__global__ __launch_bounds__(256) void k_apply(
    const unsigned short* __restrict__ s0, const float* __restrict__ Mfin,
    float* __restrict__ s2) {
  __shared__ float M[128 * 8];
  int bid = blockIdx.x;
  int b = bid / 17, ch = bid - b * 17;
  int t = threadIdx.x;
  const float4* Mb = reinterpret_cast<const float4*>(Mfin + (size_t)b * 128 * 8);
  if (t < 252) *reinterpret_cast<float4*>(&M[t * 4]) = Mb[t];
  __syncthreads();
  int i = ch * 256 + t;
  if (i >= NP) return;
  ushort4 u = reinterpret_cast<const ushort4*>(s0)[(size_t)b * NP + i];
  float s_0 = bf2f(u.x), s_1 = bf2f(u.y), s_2 = bf2f(u.z), s_3 = bf2f(u.w);
  float a0 = 0.f, a1 = 0.f, a2 = 0.f, a3 = 0.f, az = 0.f;
  int f = 0;
  float pa = 1.f;
#pragma unroll
  for (int a = 0; a <= 5; ++a) {
    float pb = pa;
#pragma unroll
    for (int b2 = 0; b2 <= 5 - a; ++b2) {
      float pc = pb;
#pragma unroll
      for (int c = 0; c <= 5 - a - b2; ++c) {
        float run = pc;
#pragma unroll
        for (int d2 = 0; d2 <= 5 - a - b2 - c; ++d2) {
          const float* mf = &M[f * 8];
          float4 m4 = *reinterpret_cast<const float4*>(mf);
          a0 = fmaf(run, m4.x, a0);
          a1 = fmaf(run, m4.y, a1);
          a2 = fmaf(run, m4.z, a2);
          a3 = fmaf(run, m4.w, a3);
          az = fmaf(run, mf[4], az);
          run *= s_3;
          ++f;
        }
        pc *= s_2;
      }
      pb *= s_1;
    }
    pa *= s_0;
  }
  float inv = 1.f / az;
  reinterpret_cast<float4*>(s2)[(size_t)b * NP + i] =
      make_float4(a0 * inv, a1 * inv, a2 * inv, a3 * inv);
}

// ---------------- Kernel 4: fused conv + pooled-combine -> outputs ----------------
// grid: b(8) x span(86) x dtile(4); block 256 = 64 d-pairs x 4 groups-of-12.
// h rows computed in registers (f32, never materialized), pooled, combined with s2.
__global__ __launch_bounds__(256) void k_fused(
    const float* __restrict__ x, const float* __restrict__ cw,
    const float* __restrict__ cb, const float* __restrict__ s2,
    float* __restrict__ out) {
  __shared__ float ws_w[64 * 132];   // 33792 B
  __shared__ float ws_x[DIN * 52];   // 3328 B
  __shared__ float ss[4][12][4];     // 768 B
  int bid = blockIdx.x;
  int dtile = bid & 3;
  int span = (bid >> 2) % NSPAN;
  int b = bid / (4 * NSPAN);
  int n0 = span * SPAN;
  int d0 = dtile * 128;
  int g0 = n0 / 12;
  int tid = threadIdx.x;

  for (int q = tid; q < 128 * 16; q += 256) {
    int dd = q >> 4, qq = (q & 15) << 2;
    float4 wv = *reinterpret_cast<const float4*>(cw + ((size_t)(d0 + dd) << 6) + qq);
    *reinterpret_cast<float4*>(&ws_w[(dd >> 1) * 132 + (dd & 1) * 64 + qq]) = wv;
  }
  const float* xb = x + (size_t)b * DIN * L_;
  for (int q = tid; q < DIN * 52; q += 256) {
    int i = q / 52, c = q - i * 52;
    int nx = n0 - 1 + c;
    ws_x[q] = (c < 51 && nx >= 0 && nx < L_) ? xb[i * L_ + nx] : 0.f;
  }
  if (tid < 192) {
    int gg = tid / 48, r = tid - gg * 48;
    int g = g0 + gg;
    ((float*)ss)[tid] = (g < NG) ? s2[((size_t)b * NP + g * 12) * 4 + r] : 0.f;
  }
  __syncthreads();

  int dp = tid & 63;
  int seg = tid >> 6;
  int g = g0 + seg;
  float acc0[12], acc1[12];
#pragma unroll
  for (int j = 0; j < 12; ++j) { acc0[j] = 0.f; acc1[j] = 0.f; }

  for (int i = 0; i < DIN; ++i) {
    const float* wp = &ws_w[dp * 132 + (i << 2)];
    float w00 = wp[0], w01 = wp[1], w02 = wp[2], w03 = wp[3];
    float w10 = wp[64], w11 = wp[65], w12 = wp[66], w13 = wp[67];
    const float* xp = &ws_x[i * 52 + seg * 12];
    float xr[16];
#pragma unroll
    for (int m = 0; m < 16; ++m) xr[m] = xp[m];
#pragma unroll
    for (int j = 0; j < 12; ++j) {
      float a0 = acc0[j], a1 = acc1[j];
      a0 = fmaf(w00, xr[j], a0);
      a0 = fmaf(w01, xr[j + 1], a0);
      a0 = fmaf(w02, xr[j + 2], a0);
      a0 = fmaf(w03, xr[j + 3], a0);
      a1 = fmaf(w10, xr[j], a1);
      a1 = fmaf(w11, xr[j + 1], a1);
      a1 = fmaf(w12, xr[j + 2], a1);
      a1 = fmaf(w13, xr[j + 3], a1);
      acc0[j] = a0; acc1[j] = a1;
    }
  }
  if (g >= NG) return;

  int d = d0 + (dp << 1);
  float cb0 = cb[d], cb1 = cb[d + 1];
  int base = g * 12;
  float hv0[12], hv1[12];
#pragma unroll
  for (int j = 0; j < 12; ++j) {
    int n = base + j;
    if (n < L_) { hv0[j] = acc0[j] + cb0; hv1[j] = acc1[j] + cb1; }
    else { hv0[j] = 0.f; hv1[j] = 0.f; }
  }
  float P20[6], P21[6], P30[4], P31[4], P40[3], P41[3];
#pragma unroll
  for (int q = 0; q < 6; ++q) {
    P20[q] = 0.5f * (hv0[2 * q] + hv0[2 * q + 1]);
    P21[q] = 0.5f * (hv1[2 * q] + hv1[2 * q + 1]);
  }
#pragma unroll
  for (int q = 0; q < 4; ++q) {
    P30[q] = (1.f / 3.f) * (hv0[3 * q] + hv0[3 * q + 1] + hv0[3 * q + 2]);
    P31[q] = (1.f / 3.f) * (hv1[3 * q] + hv1[3 * q + 1] + hv1[3 * q + 2]);
  }
#pragma unroll
  for (int q = 0; q < 3; ++q) {
    P40[q] = 0.25f * (hv0[4 * q] + hv0[4 * q + 1] + hv0[4 * q + 2] + hv0[4 * q + 3]);
    P41[q] = 0.25f * (hv1[4 * q] + hv1[4 * q + 1] + hv1[4 * q + 2] + hv1[4 * q + 3]);
  }
  float* outc = out;
  float* outd = out + (size_t)B_ * L_ * D_;
  float xq0[3] = {0.f, 0.f, 0.f}, xq1[3] = {0.f, 0.f, 0.f};
#pragma unroll
  for (int j = 0; j < 12; ++j) {
    float w0 = ss[seg][j][0], w1 = ss[seg][j][1];
    float w2 = ss[seg][j][2], w3 = ss[seg][j][3];
    float v0 = w0 * hv0[j] + w1 * P20[j >> 1] + w2 * P30[j / 3] + w3 * P40[j >> 2];
    float v1 = w0 * hv1[j] + w1 * P21[j >> 1] + w2 * P31[j / 3] + w3 * P41[j >> 2];
    int n = base + j;
    if (n < L_) {
      float2 o; o.x = v0; o.y = v1;
      *reinterpret_cast<float2*>(&outc[((size_t)b * L_ + n) * D_ + d]) = o;
    }
    xq0[j >> 2] += v0; xq1[j >> 2] += v1;
  }
#pragma unroll
  for (int q = 0; q < 3; ++q) {
    int r = 3 * g + q;
    if (r < 1024) {
      float2 o; o.x = 0.25f * xq0[q]; o.y = 0.25f * xq1[q];
      *reinterpret_cast<float2*>(&outd[((size_t)b * 1024 + r) * D_ + d]) = o;
    }
  }
}

extern "C" void kernel_launch(void* const* d_in, const int* in_sizes, int n_in,
                              void* d_out, int out_size, void* d_ws, size_t ws_size,
                              hipStream_t stream) {
  const float* x = (const float*)d_in[0];
  const float* cw = (const float*)d_in[1];
  const float* cb = (const float*)d_in[2];
  const float* sw = (const float*)d_in[3];
  const float* sb = (const float*)d_in[4];
  float* out = (float*)d_out;
  char* ws = (char*)d_ws;
  size_t off = 0;
  unsigned short* s0 = (unsigned short*)(ws + off);        // 262,656 B
  off += 262656;
  float* s2 = (float*)(ws + off);                          // 525,312 B
  off += 525312;
  float* Mpart = (float*)(ws + off);                       // 655,360 B
  off += 655360;
  float* Mfin = (float*)(ws + off);                        // 32,768 B
  off += 32768;
  float* us = (float*)(ws + off);                          // 260 B

  k_uprep<<<1, 256, 0, stream>>>(cw, cb, sw, us);
  k_scores<<<8 * 22, 192, 0, stream>>>(x, us, sb, s0);
  k_moment<<<B_ * JSP, 256, 0, stream>>>(s0, Mpart);
  k_mred<<<B_, 640, 0, stream>>>(Mpart, Mfin);
  k_apply<<<B_ * 17, 256, 0, stream>>>(s0, Mfin, s2);
  k_fused<<<B_ * NSPAN * 4, 256, 0, stream>>>(x, cw, cb, s2, out);
}